// Round 9
// baseline (237.263 us; speedup 1.0000x reference)
//
#include <hip/hip_runtime.h>

typedef __bf16    bf16x8 __attribute__((ext_vector_type(8)));
typedef __bf16    bf16x4 __attribute__((ext_vector_type(4)));
typedef float     f32x4  __attribute__((ext_vector_type(4)));

#define BM 128
#define BN 128

// async global->LDS, 16B per lane. LDS dest must be wave-uniform base + lane*16.
__device__ __forceinline__ void gload_lds16(const __bf16* g, __bf16* l) {
  __builtin_amdgcn_global_load_lds(
      (const __attribute__((address_space(1))) void*)g,
      (__attribute__((address_space(3))) void*)l,
      16, 0, 0);
}

// One launch converts x (8192 blocks) + Wq/Wk/Wv (3072 blocks) to bf16.
// Weights land concatenated in Wqkv [3072][1024] (Q rows 0.., K 1024.., V 2048..).
// Block 0 additionally zero-inits the row-sum accumulator.
__global__ void cvt_all(const float* __restrict__ x, const float* __restrict__ Wq,
                        const float* __restrict__ Wk, const float* __restrict__ Wv,
                        __bf16* __restrict__ xb, __bf16* __restrict__ Wqkv,
                        float* __restrict__ lsum) {
  int b = blockIdx.x;
  if (b == 0) {
    for (int j = threadIdx.x; j < 8192; j += 256) lsum[j] = 0.f;
  }
  const float* src;
  __bf16* dst;
  int i;
  if (b < 8192) {
    src = x; dst = xb; i = b * 256 + threadIdx.x;
  } else {
    b -= 8192;
    const int mat = b >> 10;
    i = (b & 1023) * 256 + threadIdx.x;
    src = (mat == 0) ? Wq : (mat == 1) ? Wk : Wv;
    dst = Wqkv + (size_t)mat * 1048576;
  }
  float4 v = ((const float4*)src)[i];
  bf16x4 o;
  o[0] = (__bf16)v.x; o[1] = (__bf16)v.y; o[2] = (__bf16)v.z; o[3] = (__bf16)v.w;
  ((bf16x4*)dst)[i] = o;
}

// C[m,n] = sum_k A[m,k]*B[n,k]  (both K-contiguous). 128x128 tile, BKT=128
// (64 MFMA per barrier pair). XOR source-swizzle (verified R8: conflicts -> 0):
// 16B-group g' of LDS row r holds global k-group g' ^ (r&7); fragment reads
// use group (kk*4+quad) ^ (R&7).
// MODE 0: QKV projection. grid (64, 24); bn0<2048 -> Q/K bias+bf16 row-major;
//         bn0>=2048 -> V: bias + transpose via swizzled LDS (reuses As) ->
//         coalesced bf16 store to Vt[b][d][s].
// MODE 2: scores — e = exp(v/32) stored bf16 + per-row sums into lsum
// MODE 3: PV     — fp32 store of acc * (1/lsum[row])
template<int MODE, int BKT>
__global__ __launch_bounds__(256, 2)
void gemm_bt(const __bf16* __restrict__ A, const __bf16* __restrict__ B,
             float* __restrict__ C,
             int lda, int ldb, int ldc, int K,
             long sA, long sB, long sC,
             const float* __restrict__ bq, const float* __restrict__ bk,
             const float* __restrict__ bv, float* __restrict__ lsum,
             __bf16* __restrict__ out0, __bf16* __restrict__ out1,
             __bf16* __restrict__ out2)
{
  constexpr int NCH = (BM * BKT) / (256 * 8);  // staging chunks (16B/thread each)
  constexpr int GPR = BKT / 8;                 // 16B groups per LDS row
  constexpr int RPC = 2048 / BKT;              // rows per staging chunk

  A += (long)blockIdx.z * sA;
  B += (long)blockIdx.z * sB;

  const int tid  = threadIdx.x;
  const int wave = tid >> 6;
  const int lane = tid & 63;
  const int quad = lane >> 4;
  const int l15  = lane & 15;
  const int bm0  = blockIdx.x * BM;
  const int bn0  = blockIdx.y * BN;
  const int wm   = (wave >> 1) * 64;
  const int wn   = (wave & 1) * 64;

  __shared__ __align__(16) __bf16 As[BM * BKT];
  __shared__ __align__(16) __bf16 Bs[BN * BKT];

  f32x4 acc[4][4];
#pragma unroll
  for (int i = 0; i < 4; ++i)
#pragma unroll
    for (int j = 0; j < 4; ++j)
      acc[i][j] = (f32x4){0.f, 0.f, 0.f, 0.f};

  const __bf16* Ag[NCH];
  const __bf16* Bg[NCH];
#pragma unroll
  for (int c = 0; c < NCH; ++c) {
    const int r = c * RPC + tid / GPR;
    const int g = (tid & (GPR - 1)) ^ (r & 7);
    Ag[c] = A + (size_t)(bm0 + r) * lda + g * 8;
    Bg[c] = B + (size_t)(bn0 + r) * ldb + g * 8;
  }

  for (int k0 = 0; k0 < K; k0 += BKT) {
#pragma unroll
    for (int c = 0; c < NCH; ++c) {
      gload_lds16(Ag[c] + k0, &As[c * 2048 + tid * 8]);
      gload_lds16(Bg[c] + k0, &Bs[c * 2048 + tid * 8]);
    }
    __syncthreads();

#pragma unroll
    for (int kk = 0; kk < BKT / 32; ++kk) {
      bf16x8 af[4], bfv[4];
#pragma unroll
      for (int i = 0; i < 4; ++i) {
        const int R = wm + i * 16 + l15;
        af[i] = *(const bf16x8*)&As[R * BKT + (((kk * 4 + quad) ^ (R & 7)) * 8)];
      }
#pragma unroll
      for (int i = 0; i < 4; ++i) {
        const int R = wn + i * 16 + l15;
        bfv[i] = *(const bf16x8*)&Bs[R * BKT + (((kk * 4 + quad) ^ (R & 7)) * 8)];
      }
#pragma unroll
      for (int mi = 0; mi < 4; ++mi)
#pragma unroll
        for (int ni = 0; ni < 4; ++ni)
          acc[mi][ni] = __builtin_amdgcn_mfma_f32_16x16x32_bf16(
              af[mi], bfv[ni], acc[mi][ni], 0, 0, 0);
    }
    __syncthreads();
  }

  // Epilogue. C/D layout (verified m89/m91): row m = quad*4+r, col n = lane&15.
  if (MODE == 0 && bn0 >= 2048) {
    // V projection tile: transpose through swizzled LDS (reuse As, 32 KB),
    // then coalesced store to Vt[b][d][s]. LDS_T elem = dl*128 + (G^(dl&15))*8.
    __bf16* LT = As;
    const int d0 = bn0 - 2048;
#pragma unroll
    for (int mi = 0; mi < 4; ++mi) {
      const int mb   = wm + mi * 16 + quad * 4;   // m of acc[..][0]
      const int Gw   = mb >> 3;
      const int moff = mb & 7;                    // 0 or 4
#pragma unroll
      for (int ni = 0; ni < 4; ++ni) {
        const int dl = wn + ni * 16 + l15;
        const float bias = bv[d0 + dl];
        bf16x4 tv;
#pragma unroll
        for (int r = 0; r < 4; ++r)
          tv[r] = (__bf16)(acc[mi][ni][r] + bias);
        *(bf16x4*)&LT[dl * 128 + ((Gw ^ (dl & 15)) * 8) + moff] = tv;
      }
    }
    __syncthreads();
    const int bI = bm0 >> 11;          // batch index (tile within one batch)
    const int s0 = bm0 & 2047;
#pragma unroll
    for (int j = 0; j < 8; ++j) {
      const int idx = j * 2048 + tid * 8;
      const int dl  = idx >> 7;
      const int sl  = idx & 127;
      const int sg  = sl >> 3;
      bf16x8 v = *(const bf16x8*)&LT[dl * 128 + ((sg ^ (dl & 15)) * 8)];
      *(bf16x8*)&out2[((size_t)bI * 1024 + d0 + dl) * 2048 + s0 + sl] = v;
    }
  } else if (MODE == 0) {
    // Q/K tile: bias + bf16 row-major store, split by gn>>10.
#pragma unroll
    for (int mi = 0; mi < 4; ++mi) {
#pragma unroll
      for (int ni = 0; ni < 4; ++ni) {
        const int gn  = bn0 + wn + ni * 16 + l15;
        const int mat = gn >> 10;          // uniform per tile
        const int d   = gn & 1023;
        const float bias = (mat == 0) ? bq[d] : bk[d];
        __bf16* dst = (mat == 0) ? out0 : out1;
#pragma unroll
        for (int r = 0; r < 4; ++r) {
          const int gm = bm0 + wm + mi * 16 + quad * 4 + r;
          dst[(size_t)gm * 1024 + d] = (__bf16)(acc[mi][ni][r] + bias);
        }
      }
    }
  } else if (MODE == 2) {
    // scores: w = exp(v/32) -> bf16; row sums into lsum via shfl+atomic.
#pragma unroll
    for (int mi = 0; mi < 4; ++mi) {
#pragma unroll
      for (int r = 0; r < 4; ++r) {
        const int gm = bm0 + wm + mi * 16 + quad * 4 + r;
        float part = 0.f;
#pragma unroll
        for (int ni = 0; ni < 4; ++ni) {
          const int gn = bn0 + wn + ni * 16 + l15;
          const __bf16 eb = (__bf16)__expf(acc[mi][ni][r] * 0.03125f);
          out0[(long)blockIdx.z * sC + (size_t)gm * ldc + gn] = eb;
          part += (float)eb;  // sum the rounded values PV will actually read
        }
        part += __shfl_xor(part, 1);
        part += __shfl_xor(part, 2);
        part += __shfl_xor(part, 4);
        part += __shfl_xor(part, 8);
        if (l15 == 0)
          atomicAdd(&lsum[blockIdx.z * 2048 + gm], part);
      }
    }
  } else {
    // PV: normalize by row sum while storing fp32.
#pragma unroll
    for (int mi = 0; mi < 4; ++mi) {
#pragma unroll
      for (int r = 0; r < 4; ++r) {
        const int gm = bm0 + wm + mi * 16 + quad * 4 + r;
        const float rv = 1.0f / lsum[blockIdx.z * 2048 + gm];
#pragma unroll
        for (int ni = 0; ni < 4; ++ni) {
          const int gn = bn0 + wn + ni * 16 + l15;
          C[(long)blockIdx.z * sC + (size_t)gm * ldc + gn] = acc[mi][ni][r] * rv;
        }
      }
    }
  }
}

extern "C" void kernel_launch(void* const* d_in, const int* in_sizes, int n_in,
                              void* d_out, int out_size, void* d_ws, size_t ws_size,
                              hipStream_t stream) {
  const float* x  = (const float*)d_in[0];
  const float* Wq = (const float*)d_in[1];
  const float* bq = (const float*)d_in[2];
  const float* Wk = (const float*)d_in[3];
  const float* bk = (const float*)d_in[4];
  const float* Wv = (const float*)d_in[5];
  const float* bv = (const float*)d_in[6];
  float* out = (float*)d_out;

  // ws layout:
  //  [0,16M)    Q    bf16 [8192][1024]
  //  [16,32M)   K    bf16 [8192][1024]
  //  [32,48M)   Vt   bf16 [4][1024][2048]
  //  [48,64M)   xb   bf16 (projection phase only)
  //  [64,70M)   Wqkv bf16 [3072][1024] (projection phase only)
  //  [48,80M)   Sc   bf16 [4][2048][2048] exp-weights (aliases xb/Wqkv)
  //  [110M,+32K) lsum fp32 [8192] row sums (zeroed by cvt_all block 0)
  char* ws = (char*)d_ws;
  __bf16* Q    = (__bf16*)(ws);
  __bf16* Kb   = (__bf16*)(ws + (16ull << 20));
  __bf16* Vt   = (__bf16*)(ws + (32ull << 20));
  __bf16* xb   = (__bf16*)(ws + (48ull << 20));
  __bf16* Wqkv = (__bf16*)(ws + (64ull << 20));
  __bf16* Sc   = (__bf16*)(ws + (48ull << 20));
  float*  lsum = (float*)(ws + (110ull << 20));

  dim3 blk(256);

  // fp32 -> bf16 (+ lsum zero-init), one launch
  cvt_all<<<11264, blk, 0, stream>>>(x, Wq, Wk, Wv, xb, Wqkv, lsum);

  // QKV: [8192,1024] @ [3072,1024]^T -> Q, K row-major; V transposed to Vt
  gemm_bt<0, 128><<<dim3(64, 24, 1), blk, 0, stream>>>(
      xb, Wqkv, nullptr, 1024, 1024, 0, 1024,
      0L, 0L, 0L, bq, bk, bv, nullptr, Q, Kb, Vt);

  // scores: per batch Q[2048,1024] @ K[2048,1024]^T -> bf16 exp-weights + lsum
  gemm_bt<2, 128><<<dim3(16, 16, 4), blk, 0, stream>>>(
      Q, Kb, nullptr, 1024, 1024, 2048, 1024,
      2048L * 1024, 2048L * 1024, 2048L * 2048,
      nullptr, nullptr, nullptr, lsum, Sc, nullptr, nullptr);

  // PV: per batch Sc[2048,2048](bf16) @ Vt[1024,2048]^T -> out fp32, /lsum
  gemm_bt<3, 128><<<dim3(16, 8, 4), blk, 0, stream>>>(
      Sc, Vt, out, 2048, 2048, 1024, 2048,
      2048L * 2048, 1024L * 2048, 2048L * 1024,
      nullptr, nullptr, nullptr, lsum, nullptr, nullptr, nullptr);
}